// Round 4
// baseline (104.173 us; speedup 1.0000x reference)
//
#include <hip/hip_runtime.h>

// KVCache scatter: B=8, L=4096, H=16, D=64, Q=1024 (fp32)
// out = [k_out (B,L,H,D) | v_out (B,L,H,D)] flat fp32
//
// SINGLE-KERNEL strategy: each block owns 16 output rows of one batch.
//   Prologue: scan that batch's 1024 positions (4 KB, L2-resident after the
//     first block touches it) -> 16-entry LDS inverse map (slot -> q, or -1).
//   Main: 16 row-iterations; row index k is loop-constant so the
//     scattered-vs-cache branch is wave-uniform; each thread moves one
//     f32x4 of k and one of v per row. NT hints on all big streams.
// Traffic floor: 268 MB write + 268 MB read = 536 MB -> 85 us @ 6.29 TB/s.
// Extra pos traffic: 2048 blocks x 4 KB = 8 MB, L2-hits, negligible.

#define KB 8
#define KL 4096
#define KH 16
#define KD 64
#define KQ 1024

typedef float f32x4 __attribute__((ext_vector_type(4)));

static constexpr int ROW4 = (KH * KD) / 4;     // 256 f32x4 per row
static constexpr int RPB  = 16;                 // rows per block
static constexpr int NBLK = (KB * KL) / RPB;    // 2048 blocks
static constexpr long long TOT = (long long)KB * KL * KH * KD;  // floats per tensor

__global__ __launch_bounds__(256) void kv_scatter_fused(
    const f32x4* __restrict__ kc, const f32x4* __restrict__ vc,
    const f32x4* __restrict__ kv, const f32x4* __restrict__ vv,
    const int* __restrict__ pos,
    f32x4* __restrict__ ko, f32x4* __restrict__ vo)
{
    __shared__ int inv_s[RPB];
    const int t      = threadIdx.x;
    const int row_lo = blockIdx.x * RPB;        // global row (b*L + l_lo)
    const int b      = row_lo >> 12;            // / KL
    const int l_lo   = row_lo & (KL - 1);

    if (t < RPB) inv_s[t] = -1;
    __syncthreads();
    const int* prow = pos + b * KQ;
    #pragma unroll
    for (int j = t; j < KQ; j += 256) {
        int p = prow[j] - 1;                    // 1-indexed -> 0-indexed slot
        unsigned d = (unsigned)(p - l_lo);
        if (d < (unsigned)RPB) inv_s[d] = j;
    }
    __syncthreads();

    const long long vbase = (long long)(b * KQ) << 8;   // val row base (f32x4)
    #pragma unroll
    for (int k = 0; k < RPB; ++k) {
        int q = inv_s[k];                       // wave-uniform
        long long o = ((long long)(row_lo + k) << 8) + t;
        f32x4 kx, vx;
        if (q >= 0) {
            long long s = vbase + ((long long)q << 8) + t;
            kx = __builtin_nontemporal_load(&kv[s]);
            vx = __builtin_nontemporal_load(&vv[s]);
        } else {
            kx = __builtin_nontemporal_load(&kc[o]);
            vx = __builtin_nontemporal_load(&vc[o]);
        }
        __builtin_nontemporal_store(kx, &ko[o]);
        __builtin_nontemporal_store(vx, &vo[o]);
    }
}

extern "C" void kernel_launch(void* const* d_in, const int* in_sizes, int n_in,
                              void* d_out, int out_size, void* d_ws, size_t ws_size,
                              hipStream_t stream) {
    const float* kc  = (const float*)d_in[0];
    const float* vc  = (const float*)d_in[1];
    const float* kv  = (const float*)d_in[2];
    const float* vv  = (const float*)d_in[3];
    const int*   pos = (const int*)d_in[4];

    float* ko = (float*)d_out;
    float* vo = ko + TOT;

    kv_scatter_fused<<<NBLK, 256, 0, stream>>>(
        (const f32x4*)kc, (const f32x4*)vc,
        (const f32x4*)kv, (const f32x4*)vv,
        pos, (f32x4*)ko, (f32x4*)vo);
}